// Round 1
// 749.938 us; speedup vs baseline: 1.0934x; 1.0934x over previous
//
#include <hip/hip_runtime.h>
#include <hip/hip_bf16.h>
#include <stdint.h>
#include <stddef.h>

// ---------------------------------------------------------------------------
// Linear2MPO: y = x @ M + bias, M = TT-contraction of 5 cores -> [768, 3072]
// Plan (this round: TT-chain rework):
//   1) tt_gemm (old, tiny): c0 x c1 -> t2 [192,192] row-major.
//   2) b34_build: B34[r3, (i3 i4)*24+(o3 o4)] = sum_r4 c3*c4  [384,384].
//   3) tt_fast<2>: t2 @ c2 -> t3 [6144,384] row-major (coalesced f4 epilogue).
//   4) tt_fast<3>: t3 @ B34 -> Mt bf16 [3072,768] direct scatter.
//      tt_fast: 64x128 tile, 4x8/thread, A transposed into LDS at staging,
//      reg double-buffered global loads, all-f4 LDS reads.
//   5) cast x fp32 -> bf16.
//   6) mpo_gemm: bf16 MFMA 16x16x32, 128x128 tile, BK=64, global_load_lds
//      width-16, XOR k-seg swizzle + NEW bijective XCD blockIdx swizzle.
// ---------------------------------------------------------------------------

typedef __attribute__((ext_vector_type(8))) short short8;
typedef __attribute__((ext_vector_type(4))) float floatx4;

#define DEVINL __device__ __forceinline__

DEVINL void gload_lds16(const void* g, void* l) {
  __builtin_amdgcn_global_load_lds(
      (const __attribute__((address_space(1))) unsigned int*)g,
      (__attribute__((address_space(3))) unsigned int*)l, 16, 0, 0);
}

DEVINL unsigned short f2bf(float f) {
  unsigned int u = __float_as_uint(f);
  u = u + 0x7fffu + ((u >> 16) & 1u);  // RNE
  return (unsigned short)(u >> 16);
}

// ---------------- x fp32 -> bf16 (vectorized x4) ----------------
__global__ __launch_bounds__(256) void cast_x_kernel(
    const float4* __restrict__ x4, ushort4* __restrict__ xb4, int n4) {
  int i = blockIdx.x * blockDim.x + threadIdx.x;
  if (i >= n4) return;
  float4 v = x4[i];
  ushort4 o;
  o.x = f2bf(v.x); o.y = f2bf(v.y); o.z = f2bf(v.z); o.w = f2bf(v.w);
  xb4[i] = o;
}

// ---------------- tiny step1: generic GEMM + scatter (unchanged) ----------
__global__ __launch_bounds__(256) void tt_gemm(
    const float* __restrict__ A, const float* __restrict__ B,
    float* __restrict__ C, unsigned short* __restrict__ Ct,
    int M, int K, int N, int Odim, int idim, int odim, int qdim,
    int final_bf16_transpose) {
  __shared__ float sA[64][17];
  __shared__ float sB[16][68];
  const int tid = threadIdx.x;
  const int tx = tid & 15, ty = tid >> 4;
  const int bm = blockIdx.y, bn = blockIdx.x;
  float acc[4][4] = {};
  const int arow = tid >> 2;          // 0..63
  const int acol = (tid & 3) * 4;     // 0,4,8,12
  const int brow = tid >> 4;          // 0..15
  const int bcol = (tid & 15) * 4;    // 0..60

  for (int k0 = 0; k0 < K; k0 += 16) {
    {
      int r = bm * 64 + arow;
#pragma unroll
      for (int j = 0; j < 4; j++) {
        int k = k0 + acol + j;
        sA[arow][acol + j] = (r < M && k < K) ? A[(size_t)r * K + k] : 0.f;
      }
      int kb = k0 + brow;
#pragma unroll
      for (int j = 0; j < 4; j++) {
        int c = bn * 64 + bcol + j;
        sB[brow][bcol + j] = (kb < K && c < N) ? B[(size_t)kb * N + c] : 0.f;
      }
    }
    __syncthreads();
#pragma unroll 4
    for (int kb = 0; kb < 16; kb++) {
      float ra[4], rb[4];
#pragma unroll
      for (int r = 0; r < 4; r++) ra[r] = sA[ty * 4 + r][kb];
#pragma unroll
      for (int c = 0; c < 4; c++) rb[c] = sB[kb][tx * 4 + c];
#pragma unroll
      for (int r = 0; r < 4; r++)
#pragma unroll
        for (int c = 0; c < 4; c++) acc[r][c] += ra[r] * rb[c];
    }
    __syncthreads();
  }

  const int oq = odim * qdim;
#pragma unroll
  for (int r = 0; r < 4; r++) {
    int row = bm * 64 + ty * 4 + r;
    if (row >= M) continue;
    int I = row / Odim, O = row - I * Odim;
#pragma unroll
    for (int c = 0; c < 4; c++) {
      int col = bn * 64 + tx * 4 + c;
      if (col >= N) continue;
      int i = col / oq; int rem = col - i * oq;
      int o = rem / qdim; int q = rem - o * qdim;
      size_t dst = ((((size_t)I * idim + i) * Odim + O) * (size_t)odim + o) * qdim + q;
      if (final_bf16_transpose) {
        size_t in_ = dst / 3072, out_ = dst - in_ * 3072;
        Ct[out_ * 768 + in_] = f2bf(acc[r][c]);
      } else {
        C[dst] = acc[r][c];
      }
    }
  }
}

// ---------------- B34 = c3 x c4 -> [384, 384] (col = i34*24 + o34) --------
// B34[r3][ (i3*4+i4)*24 + (o3*4+o4) ] = sum_r4 c3[r3,i3,o3,r4]*c4[r4,i4,o4]
__global__ __launch_bounds__(256) void b34_build(
    const float* __restrict__ c3, const float* __restrict__ c4,
    float* __restrict__ B34) {
  int e = blockIdx.x * 256 + threadIdx.x;       // 576*256 = 147456 exact
  int r3 = e / 384; int c = e - r3 * 384;
  int i34 = c / 24, o34 = c - i34 * 24;
  int i3 = i34 >> 2, i4 = i34 & 3;
  int o3 = o34 >> 2, o4 = o34 & 3;
  const float* p3 = c3 + (((size_t)r3 * 4 + i3) * 6 + o3) * 16;  // stride 1 in r4
  const float* p4 = c4 + i4 * 4 + o4;                            // stride 16 in r4
  float s = 0.f;
#pragma unroll
  for (int r4 = 0; r4 < 16; r4++) s += p3[r4] * p4[r4 * 16];
  B34[e] = s;
}

// ---------------- fast fp32 GEMM + scatter for steps 2 / 3' ----------------
// STEP==2: A=t2 [192,192], B=c2 [192,12288], C=t3 [6144,384] row-major.
// STEP==3: A=t3 [6144,384], B=B34 [384,384], Ct=Mt bf16 [3072,768].
// Tile 64(m) x 128(n), BK=32, 256 thr, 4x8 per thread.
// LDS: sAt[k][m] (A transposed at staging), sB[k][n] chunk-swizzled.
template <int STEP>
__global__ __launch_bounds__(256) void tt_fast(
    const float* __restrict__ A, const float* __restrict__ B,
    float* __restrict__ C, unsigned short* __restrict__ Ct) {
  constexpr int K  = (STEP == 2) ? 192 : 384;
  constexpr int NN = (STEP == 2) ? 12288 : 384;
  constexpr int NT = K / 32;
  __shared__ __align__(16) float sAt[32][68];
  __shared__ __align__(16) float sB[32][144];
  const int tid = threadIdx.x;
  const int tx = tid & 15, ty = tid >> 4;
  const int bm = blockIdx.y, bn = blockIdx.x;

  const int arow = tid >> 3;        // 0..31
  const int akq  = (tid & 7) * 4;   // k sub-offset 0..28
  const int brow = tid >> 5;        // 0..7
  const int bq   = tid & 31;        // float4 index in 128-wide row
  const float* gA = A + (size_t)(bm * 64 + arow) * K + akq;
  const float* gB = B + (size_t)brow * NN + bn * 128 + bq * 4;
  const int bso = bq * 4 + ((bq >> 3) << 2);          // swizzled store offset
  const int rb_off = tx * 8 + ((tx >> 2) << 2);       // swizzled read offset

  // prefetch tile 0 into registers
  float4 a0 = *(const float4*)(gA);
  float4 a1 = *(const float4*)(gA + (size_t)32 * K);
  float4 b0 = *(const float4*)(gB);
  float4 b1 = *(const float4*)(gB + (size_t)8 * NN);
  float4 b2 = *(const float4*)(gB + (size_t)16 * NN);
  float4 b3 = *(const float4*)(gB + (size_t)24 * NN);

  float acc[4][8];
#pragma unroll
  for (int r = 0; r < 4; r++)
#pragma unroll
    for (int c = 0; c < 8; c++) acc[r][c] = 0.f;

  for (int t = 0; t < NT; t++) {
    __syncthreads();  // previous tile's reads done
    sAt[akq + 0][arow]      = a0.x;
    sAt[akq + 1][arow]      = a0.y;
    sAt[akq + 2][arow]      = a0.z;
    sAt[akq + 3][arow]      = a0.w;
    sAt[akq + 0][arow + 32] = a1.x;
    sAt[akq + 1][arow + 32] = a1.y;
    sAt[akq + 2][arow + 32] = a1.z;
    sAt[akq + 3][arow + 32] = a1.w;
    *(float4*)&sB[brow][bso]      = b0;
    *(float4*)&sB[brow + 8][bso]  = b1;
    *(float4*)&sB[brow + 16][bso] = b2;
    *(float4*)&sB[brow + 24][bso] = b3;
    __syncthreads();
    if (t + 1 < NT) {   // issue next-tile loads before compute (latency hide)
      const float* pA = gA + (t + 1) * 32;
      a0 = *(const float4*)(pA);
      a1 = *(const float4*)(pA + (size_t)32 * K);
      const float* pB = gB + (size_t)(t + 1) * 32 * NN;
      b0 = *(const float4*)(pB);
      b1 = *(const float4*)(pB + (size_t)8 * NN);
      b2 = *(const float4*)(pB + (size_t)16 * NN);
      b3 = *(const float4*)(pB + (size_t)24 * NN);
    }
#pragma unroll 8
    for (int k = 0; k < 32; k++) {
      const float4 ra  = *(const float4*)&sAt[k][ty * 4];
      const float4 rb0 = *(const float4*)&sB[k][rb_off];
      const float4 rb1 = *(const float4*)&sB[k][rb_off + 4];
      const float av[4] = {ra.x, ra.y, ra.z, ra.w};
      const float bv[8] = {rb0.x, rb0.y, rb0.z, rb0.w,
                           rb1.x, rb1.y, rb1.z, rb1.w};
#pragma unroll
      for (int r = 0; r < 4; r++)
#pragma unroll
        for (int c = 0; c < 8; c++) acc[r][c] += av[r] * bv[c];
    }
  }

  if constexpr (STEP == 2) {
    // C row m=(I12,O16); col=(i2,o2,r3). t3 row-major [6144,384]:
    // drow = (I*4+i2)*128 + O*8+o2 ; dst = drow*384 + r3 (f4 stores)
    const int colbase = bn * 128 + tx * 8;
    const int g = colbase / 384;            // constant across the 8 cols
    const int r3 = colbase - g * 384;
    const int i2 = g >> 3, o2 = g & 7;
#pragma unroll
    for (int r = 0; r < 4; r++) {
      int m = bm * 64 + ty * 4 + r;
      int I = m >> 4, O = m & 15;
      size_t drow = (size_t)((I * 4 + i2) * 128 + O * 8 + o2);
      float4 v0 = {acc[r][0], acc[r][1], acc[r][2], acc[r][3]};
      float4 v1 = {acc[r][4], acc[r][5], acc[r][6], acc[r][7]};
      *(float4*)(C + drow * 384 + r3)     = v0;
      *(float4*)(C + drow * 384 + r3 + 4) = v1;
    }
  } else {
    // C row m2=(Iin48,Oout128); col=(i34,o34). Mt[out*768+in] bf16,
    // in = Iin*16+i34, out = Oout*24+o34.
    const int colbase = bn * 128 + tx * 8;
#pragma unroll
    for (int r = 0; r < 4; r++) {
      int m2 = bm * 64 + ty * 4 + r;
      int Iin = m2 >> 7, Oout = m2 & 127;
#pragma unroll
      for (int c = 0; c < 8; c++) {
        int col = colbase + c;
        int i34 = col / 24;
        int o34 = col - i34 * 24;
        Ct[(size_t)(Oout * 24 + o34) * 768 + Iin * 16 + i34] = f2bf(acc[r][c]);
      }
    }
  }
}

// ---------------- main GEMM: out[32768,3072] = Xb @ Mt^T + bias ----------------
// Xb [32768,768] bf16 row-major; Mt [3072,768] bf16 row-major (K-contiguous).
// Block: 256 thr = 4 waves, tile 128x128, BK=64.
// LDS layout [row][kseg], kseg XOR-swizzled by (row&7); identity lane->LDS
// mapping preserved for global_load_lds (swizzle applied to global src addr).
// NEW: bijective XCD-aware blockIdx swizzle (nwg = 6144 = 8*768).
__global__ __launch_bounds__(256) void mpo_gemm(
    const unsigned short* __restrict__ Xb,
    const unsigned short* __restrict__ Mt,
    const float* __restrict__ bias,
    float* __restrict__ out) {
  __shared__ __align__(16) unsigned short sA[128 * 64];
  __shared__ __align__(16) unsigned short sB[128 * 64];
  const int tid = threadIdx.x;
  const int lane = tid & 63;
  const int wave = tid >> 6;       // 0..3
  // XCD swizzle: dispatch-linear id -> contiguous chunk per XCD
  const int lin = blockIdx.y * 24 + blockIdx.x;   // grid (24, 256)
  const int nid = (lin & 7) * 768 + (lin >> 3);   // 6144/8 = 768 per XCD
  const int bn = nid % 24;
  const int bm = nid / 24;

  // staging role: waves 0,1 -> A halves 0,1 ; waves 2,3 -> B halves 0,1
  const int is_b = wave >> 1;
  const int half = wave & 1;
  const unsigned short* gbase = is_b ? Mt : Xb;
  unsigned short* lds_base = is_b ? sB : sA;
  const int tile_row0 = (is_b ? bn : bm) * 128 + half * 64;
  const int lrow = lane >> 3;                 // 0..7 within 8-row chunk
  const int segg = (lane & 7) ^ lrow;         // swizzled global k-segment
  const unsigned short* gptr[8];
#pragma unroll
  for (int j = 0; j < 8; j++)
    gptr[j] = gbase + (size_t)(tile_row0 + j * 8 + lrow) * 768 + segg * 8;

  // compute role: wave (wm,wn) owns 64x64 quadrant
  const int wm = wave & 1, wn = wave >> 1;
  const int row15 = lane & 15;
  const int kg = lane >> 4;                   // 0..3

  floatx4 acc[4][4];
#pragma unroll
  for (int mi = 0; mi < 4; mi++)
#pragma unroll
    for (int ni = 0; ni < 4; ni++) acc[mi][ni] = (floatx4){0.f, 0.f, 0.f, 0.f};

  for (int k0 = 0; k0 < 768; k0 += 64) {
    __syncthreads();  // previous compute done before LDS overwrite
#pragma unroll
    for (int j = 0; j < 8; j++) {
      unsigned short* l = lds_base + (half * 64 + j * 8) * 64;  // wave-uniform
      gload_lds16(gptr[j] + k0, l);
    }
    __syncthreads();  // staged data visible

#pragma unroll
    for (int kk = 0; kk < 2; kk++) {
      short8 af[4], bfv[4];
#pragma unroll
      for (int mi = 0; mi < 4; mi++) {
        int row = wm * 64 + mi * 16 + row15;
        int sp = (kk * 4 + kg) ^ (row & 7);
        af[mi] = *(const short8*)(sA + row * 64 + sp * 8);
      }
#pragma unroll
      for (int ni = 0; ni < 4; ni++) {
        int row = wn * 64 + ni * 16 + row15;
        int sp = (kk * 4 + kg) ^ (row & 7);
        bfv[ni] = *(const short8*)(sB + row * 64 + sp * 8);
      }
#pragma unroll
      for (int mi = 0; mi < 4; mi++)
#pragma unroll
        for (int ni = 0; ni < 4; ni++)
          acc[mi][ni] = __builtin_amdgcn_mfma_f32_16x16x32_bf16(
              af[mi], bfv[ni], acc[mi][ni], 0, 0, 0);
    }
  }

  // epilogue: C/D layout col=lane&15, row=(lane>>4)*4+reg
  const int crow = (lane >> 4) * 4;
  const int ccol = lane & 15;
#pragma unroll
  for (int ni = 0; ni < 4; ni++) {
    int col = bn * 128 + wn * 64 + ni * 16 + ccol;
    float bv = bias[col];
#pragma unroll
    for (int mi = 0; mi < 4; mi++) {
      int row0 = bm * 128 + wm * 64 + mi * 16 + crow;
      floatx4 v = acc[mi][ni];
#pragma unroll
      for (int r = 0; r < 4; r++)
        out[(size_t)(row0 + r) * 3072 + col] = v[r] + bv;
    }
  }
}

// ---------------- workspace layout (bytes) ----------------
#define OFF_T2  0u                      // 147,456 B   (t2: 192*192 fp32)
#define OFF_T3  147456u                 // 9,437,184 B (t3: 6144*384 fp32)
#define OFF_B34 9584640u                // 589,824 B   (B34: 384*384 fp32)
#define OFF_MT  10174464u               // 4,718,592 B (Mt: 3072*768 bf16)
#define OFF_XB  14893056u               // 50,331,648 B (xb: 32768*768 bf16)
// total: 65,224,704 B

extern "C" void kernel_launch(void* const* d_in, const int* in_sizes, int n_in,
                              void* d_out, int out_size, void* d_ws, size_t ws_size,
                              hipStream_t stream) {
  const float* x  = (const float*)d_in[0];
  const float* c0 = (const float*)d_in[1];
  const float* c1 = (const float*)d_in[2];
  const float* c2 = (const float*)d_in[3];
  const float* c3 = (const float*)d_in[4];
  const float* c4 = (const float*)d_in[5];
  const float* bias = (const float*)d_in[6];
  float* out = (float*)d_out;
  char* ws = (char*)d_ws;

  float* t2 = (float*)(ws + OFF_T2);
  float* t3 = (float*)(ws + OFF_T3);
  float* B34 = (float*)(ws + OFF_B34);
  unsigned short* Mt = (unsigned short*)(ws + OFF_MT);
  unsigned short* xb = (unsigned short*)(ws + OFF_XB);

  // 1) x -> bf16 (25,165,824 elems / 4 per thread)
  cast_x_kernel<<<dim3(24576), dim3(256), 0, stream>>>(
      (const float4*)x, (ushort4*)xb, 6291456);

  // 2) step1 (tiny): c0 x c1 -> t2 [192,192] row-major (q contiguous)
  tt_gemm<<<dim3(48, 1), dim3(256), 0, stream>>>(
      c0, c1, t2, nullptr, 12, 12, 3072, 4, 4, 4, 192, 0);

  // 3) B34 = c3 x c4 -> [384, 384]
  b34_build<<<dim3(576), dim3(256), 0, stream>>>(c3, c4, B34);

  // 4) step2: t2 @ c2 -> t3 [6144, 384] row-major. grid (N/128, M/64)
  tt_fast<2><<<dim3(96, 3), dim3(256), 0, stream>>>(t2, c2, t3, nullptr);

  // 5) step3': t3 @ B34 -> Mt bf16. grid (384/128, 6144/64)
  tt_fast<3><<<dim3(3, 96), dim3(256), 0, stream>>>(t3, B34, nullptr, Mt);

  // 6) main GEMM: grid (N/128=24, M/128=256), XCD-swizzled inside
  mpo_gemm<<<dim3(24, 256), dim3(256), 0, stream>>>(xb, Mt, bias, out);
}

// Round 2
// 672.519 us; speedup vs baseline: 1.2193x; 1.1151x over previous
//
#include <hip/hip_runtime.h>
#include <hip/hip_bf16.h>
#include <stdint.h>
#include <stddef.h>

// ---------------------------------------------------------------------------
// Linear2MPO: y = x @ M + bias, M = TT-contraction of 5 cores -> [768, 3072]
//   1) tt_gemm (tiny): c0 x c1 -> t2 [192,192].
//   2) b34_build: B34 = c3 x c4 [384,384].
//   3) tt_fast<2>: t2 @ c2 -> t3 [6144,384].
//   4) tt_fast<3>: t3 @ B34 -> Mt bf16 [3072,768].
//   5) cast x fp32 -> bf16.
//   6) mpo_gemm256: NEW 8-phase 256x256 bf16 MFMA GEMM (BK=64, 8 waves,
//      128KB dbuf LDS, counted vmcnt(4), setprio, XOR k-seg swizzle).
//      XCD swizzle REVERTED (round-1 counters: FETCH +75MB, dur +20us).
// ---------------------------------------------------------------------------

typedef __attribute__((ext_vector_type(8))) short short8;
typedef __attribute__((ext_vector_type(4))) float floatx4;

#define DEVINL __device__ __forceinline__

DEVINL void gload_lds16(const void* g, void* l) {
  __builtin_amdgcn_global_load_lds(
      (const __attribute__((address_space(1))) unsigned int*)g,
      (__attribute__((address_space(3))) unsigned int*)l, 16, 0, 0);
}

DEVINL unsigned short f2bf(float f) {
  unsigned int u = __float_as_uint(f);
  u = u + 0x7fffu + ((u >> 16) & 1u);  // RNE
  return (unsigned short)(u >> 16);
}

// ---------------- x fp32 -> bf16 (vectorized x4) ----------------
__global__ __launch_bounds__(256) void cast_x_kernel(
    const float4* __restrict__ x4, ushort4* __restrict__ xb4, int n4) {
  int i = blockIdx.x * blockDim.x + threadIdx.x;
  if (i >= n4) return;
  float4 v = x4[i];
  ushort4 o;
  o.x = f2bf(v.x); o.y = f2bf(v.y); o.z = f2bf(v.z); o.w = f2bf(v.w);
  xb4[i] = o;
}

// ---------------- tiny step1: generic GEMM + scatter ----------------------
__global__ __launch_bounds__(256) void tt_gemm(
    const float* __restrict__ A, const float* __restrict__ B,
    float* __restrict__ C, unsigned short* __restrict__ Ct,
    int M, int K, int N, int Odim, int idim, int odim, int qdim,
    int final_bf16_transpose) {
  __shared__ float sA[64][17];
  __shared__ float sB[16][68];
  const int tid = threadIdx.x;
  const int tx = tid & 15, ty = tid >> 4;
  const int bm = blockIdx.y, bn = blockIdx.x;
  float acc[4][4] = {};
  const int arow = tid >> 2;
  const int acol = (tid & 3) * 4;
  const int brow = tid >> 4;
  const int bcol = (tid & 15) * 4;

  for (int k0 = 0; k0 < K; k0 += 16) {
    {
      int r = bm * 64 + arow;
#pragma unroll
      for (int j = 0; j < 4; j++) {
        int k = k0 + acol + j;
        sA[arow][acol + j] = (r < M && k < K) ? A[(size_t)r * K + k] : 0.f;
      }
      int kb = k0 + brow;
#pragma unroll
      for (int j = 0; j < 4; j++) {
        int c = bn * 64 + bcol + j;
        sB[brow][bcol + j] = (kb < K && c < N) ? B[(size_t)kb * N + c] : 0.f;
      }
    }
    __syncthreads();
#pragma unroll 4
    for (int kb = 0; kb < 16; kb++) {
      float ra[4], rb[4];
#pragma unroll
      for (int r = 0; r < 4; r++) ra[r] = sA[ty * 4 + r][kb];
#pragma unroll
      for (int c = 0; c < 4; c++) rb[c] = sB[kb][tx * 4 + c];
#pragma unroll
      for (int r = 0; r < 4; r++)
#pragma unroll
        for (int c = 0; c < 4; c++) acc[r][c] += ra[r] * rb[c];
    }
    __syncthreads();
  }

  const int oq = odim * qdim;
#pragma unroll
  for (int r = 0; r < 4; r++) {
    int row = bm * 64 + ty * 4 + r;
    if (row >= M) continue;
    int I = row / Odim, O = row - I * Odim;
#pragma unroll
    for (int c = 0; c < 4; c++) {
      int col = bn * 64 + tx * 4 + c;
      if (col >= N) continue;
      int i = col / oq; int rem = col - i * oq;
      int o = rem / qdim; int q = rem - o * qdim;
      size_t dst = ((((size_t)I * idim + i) * Odim + O) * (size_t)odim + o) * qdim + q;
      if (final_bf16_transpose) {
        size_t in_ = dst / 3072, out_ = dst - in_ * 3072;
        Ct[out_ * 768 + in_] = f2bf(acc[r][c]);
      } else {
        C[dst] = acc[r][c];
      }
    }
  }
}

// ---------------- B34 = c3 x c4 -> [384, 384] ------------------------------
__global__ __launch_bounds__(256) void b34_build(
    const float* __restrict__ c3, const float* __restrict__ c4,
    float* __restrict__ B34) {
  int e = blockIdx.x * 256 + threadIdx.x;       // 576*256 = 147456 exact
  int r3 = e / 384; int c = e - r3 * 384;
  int i34 = c / 24, o34 = c - i34 * 24;
  int i3 = i34 >> 2, i4 = i34 & 3;
  int o3 = o34 >> 2, o4 = o34 & 3;
  const float* p3 = c3 + (((size_t)r3 * 4 + i3) * 6 + o3) * 16;
  const float* p4 = c4 + i4 * 4 + o4;
  float s = 0.f;
#pragma unroll
  for (int r4 = 0; r4 < 16; r4++) s += p3[r4] * p4[r4 * 16];
  B34[e] = s;
}

// ---------------- fast fp32 GEMM + scatter for steps 2 / 3' ----------------
template <int STEP>
__global__ __launch_bounds__(256) void tt_fast(
    const float* __restrict__ A, const float* __restrict__ B,
    float* __restrict__ C, unsigned short* __restrict__ Ct) {
  constexpr int K  = (STEP == 2) ? 192 : 384;
  constexpr int NN = (STEP == 2) ? 12288 : 384;
  constexpr int NT = K / 32;
  __shared__ __align__(16) float sAt[32][68];
  __shared__ __align__(16) float sB[32][144];
  const int tid = threadIdx.x;
  const int tx = tid & 15, ty = tid >> 4;
  const int bm = blockIdx.y, bn = blockIdx.x;

  const int arow = tid >> 3;
  const int akq  = (tid & 7) * 4;
  const int brow = tid >> 5;
  const int bq   = tid & 31;
  const float* gA = A + (size_t)(bm * 64 + arow) * K + akq;
  const float* gB = B + (size_t)brow * NN + bn * 128 + bq * 4;
  const int bso = bq * 4 + ((bq >> 3) << 2);
  const int rb_off = tx * 8 + ((tx >> 2) << 2);

  float4 a0 = *(const float4*)(gA);
  float4 a1 = *(const float4*)(gA + (size_t)32 * K);
  float4 b0 = *(const float4*)(gB);
  float4 b1 = *(const float4*)(gB + (size_t)8 * NN);
  float4 b2 = *(const float4*)(gB + (size_t)16 * NN);
  float4 b3 = *(const float4*)(gB + (size_t)24 * NN);

  float acc[4][8];
#pragma unroll
  for (int r = 0; r < 4; r++)
#pragma unroll
    for (int c = 0; c < 8; c++) acc[r][c] = 0.f;

  for (int t = 0; t < NT; t++) {
    __syncthreads();
    sAt[akq + 0][arow]      = a0.x;
    sAt[akq + 1][arow]      = a0.y;
    sAt[akq + 2][arow]      = a0.z;
    sAt[akq + 3][arow]      = a0.w;
    sAt[akq + 0][arow + 32] = a1.x;
    sAt[akq + 1][arow + 32] = a1.y;
    sAt[akq + 2][arow + 32] = a1.z;
    sAt[akq + 3][arow + 32] = a1.w;
    *(float4*)&sB[brow][bso]      = b0;
    *(float4*)&sB[brow + 8][bso]  = b1;
    *(float4*)&sB[brow + 16][bso] = b2;
    *(float4*)&sB[brow + 24][bso] = b3;
    __syncthreads();
    if (t + 1 < NT) {
      const float* pA = gA + (t + 1) * 32;
      a0 = *(const float4*)(pA);
      a1 = *(const float4*)(pA + (size_t)32 * K);
      const float* pB = gB + (size_t)(t + 1) * 32 * NN;
      b0 = *(const float4*)(pB);
      b1 = *(const float4*)(pB + (size_t)8 * NN);
      b2 = *(const float4*)(pB + (size_t)16 * NN);
      b3 = *(const float4*)(pB + (size_t)24 * NN);
    }
#pragma unroll 8
    for (int k = 0; k < 32; k++) {
      const float4 ra  = *(const float4*)&sAt[k][ty * 4];
      const float4 rb0 = *(const float4*)&sB[k][rb_off];
      const float4 rb1 = *(const float4*)&sB[k][rb_off + 4];
      const float av[4] = {ra.x, ra.y, ra.z, ra.w};
      const float bv[8] = {rb0.x, rb0.y, rb0.z, rb0.w,
                           rb1.x, rb1.y, rb1.z, rb1.w};
#pragma unroll
      for (int r = 0; r < 4; r++)
#pragma unroll
        for (int c = 0; c < 8; c++) acc[r][c] += av[r] * bv[c];
    }
  }

  if constexpr (STEP == 2) {
    const int colbase = bn * 128 + tx * 8;
    const int g = colbase / 384;
    const int r3 = colbase - g * 384;
    const int i2 = g >> 3, o2 = g & 7;
#pragma unroll
    for (int r = 0; r < 4; r++) {
      int m = bm * 64 + ty * 4 + r;
      int I = m >> 4, O = m & 15;
      size_t drow = (size_t)((I * 4 + i2) * 128 + O * 8 + o2);
      float4 v0 = {acc[r][0], acc[r][1], acc[r][2], acc[r][3]};
      float4 v1 = {acc[r][4], acc[r][5], acc[r][6], acc[r][7]};
      *(float4*)(C + drow * 384 + r3)     = v0;
      *(float4*)(C + drow * 384 + r3 + 4) = v1;
    }
  } else {
    const int colbase = bn * 128 + tx * 8;
#pragma unroll
    for (int r = 0; r < 4; r++) {
      int m2 = bm * 64 + ty * 4 + r;
      int Iin = m2 >> 7, Oout = m2 & 127;
#pragma unroll
      for (int c = 0; c < 8; c++) {
        int col = colbase + c;
        int i34 = col / 24;
        int o34 = col - i34 * 24;
        Ct[(size_t)(Oout * 24 + o34) * 768 + Iin * 16 + i34] = f2bf(acc[r][c]);
      }
    }
  }
}

// ---------------- main GEMM: 8-phase 256x256 schedule ----------------------
// out[32768,3072] = Xb[32768,768]bf16 @ Mt[3072,768]bf16^T + bias, fp32 out.
// 512 thr = 8 waves (2M x 4N), BM=BN=256, BK=64, 12 K-tiles.
// LDS 128KB: A[par][half][128][64] + B[par][half][128][64] bf16, XOR k-seg
// swizzle (LDS[r][s] = G[r][s^(r&7)], applied via pre-swizzled global src).
// Per K-tile: 4 phases {ds_read subtile | stage 1 half-tile | bar |
// setprio(1) 16xMFMA setprio(0) | bar}; ONE counted s_waitcnt vmcnt(4) per
// K-tile boundary (staging runs 2 phases ahead of the wait: A(t+1) at
// P1/P2, B(t+2) at P3/P4).
#define KTILES 12

#define STAGE_A(PAR, H, KT) do {                                              \
    const unsigned short* g_ = gA + (size_t)((H) * 128) * 768 + (KT) * 64;    \
    unsigned short* l_ = smA + ((PAR) * 2 + (H)) * 8192 + wave * 1024;        \
    gload_lds16(g_, l_);                                                      \
    gload_lds16(g_ + 8 * 768, l_ + 512);                                      \
  } while (0)

#define STAGE_B(PAR, H, KT) do {                                              \
    const unsigned short* g_ = gB + (size_t)((H) * 128) * 768 + (KT) * 64;    \
    unsigned short* l_ = smB + ((PAR) * 2 + (H)) * 8192 + wave * 1024;        \
    gload_lds16(g_, l_);                                                      \
    gload_lds16(g_ + 8 * 768, l_ + 512);                                      \
  } while (0)

#define PH_BAR() do {                                                         \
    asm volatile("" ::: "memory");                                            \
    __builtin_amdgcn_s_barrier();                                             \
    asm volatile("" ::: "memory");                                            \
  } while (0)

#define MFMA8(M0) do {                                                        \
    __builtin_amdgcn_s_setprio(1);                                            \
    _Pragma("unroll")                                                         \
    for (int mi = 0; mi < 2; mi++)                                            \
      _Pragma("unroll")                                                       \
      for (int ni = 0; ni < 4; ni++)                                          \
        _Pragma("unroll")                                                     \
        for (int ks = 0; ks < 2; ks++)                                        \
          acc[(M0) + mi][ni] = __builtin_amdgcn_mfma_f32_16x16x32_bf16(       \
              afr[mi][ks], bfr[ni][ks], acc[(M0) + mi][ni], 0, 0, 0);         \
    __builtin_amdgcn_s_setprio(0);                                            \
  } while (0)

#define LOAD_A2(M0) do {                                                      \
    afr[0][0] = *(const short8*)(Ab + (M0) * 1024 + sp0);                     \
    afr[0][1] = *(const short8*)(Ab + (M0) * 1024 + sp1);                     \
    afr[1][0] = *(const short8*)(Ab + ((M0) + 1) * 1024 + sp0);               \
    afr[1][1] = *(const short8*)(Ab + ((M0) + 1) * 1024 + sp1);               \
  } while (0)

#define TILE_STEP(T, P) do {                                                  \
    const unsigned short* Ab = smA + (P) * 16384 + wm * 8192 + row15 * 64;    \
    const unsigned short* Bb = smB + (P) * 16384 + hb * 8192 +                \
                               ((wn & 1) * 64 + row15) * 64;                  \
    short8 bfr[4][2], afr[2][2];                                              \
    /* phase 1 */                                                             \
    _Pragma("unroll")                                                         \
    for (int ni = 0; ni < 4; ni++) {                                          \
      bfr[ni][0] = *(const short8*)(Bb + ni * 1024 + sp0);                    \
      bfr[ni][1] = *(const short8*)(Bb + ni * 1024 + sp1);                    \
    }                                                                         \
    LOAD_A2(0);                                                               \
    if ((T) + 1 < KTILES) STAGE_A((P) ^ 1, 0, (T) + 1);                       \
    PH_BAR();                                                                 \
    MFMA8(0);                                                                 \
    PH_BAR();                                                                 \
    /* phase 2 */                                                             \
    LOAD_A2(2);                                                               \
    if ((T) + 1 < KTILES) STAGE_A((P) ^ 1, 1, (T) + 1);                       \
    PH_BAR();                                                                 \
    MFMA8(2);                                                                 \
    PH_BAR();                                                                 \
    /* phase 3 */                                                             \
    LOAD_A2(4);                                                               \
    if ((T) + 2 < KTILES) STAGE_B((P), 0, (T) + 2);                           \
    PH_BAR();                                                                 \
    MFMA8(4);                                                                 \
    PH_BAR();                                                                 \
    /* phase 4 */                                                             \
    LOAD_A2(6);                                                               \
    if ((T) + 2 < KTILES) STAGE_B((P), 1, (T) + 2);                           \
    PH_BAR();                                                                 \
    MFMA8(6);                                                                 \
    asm volatile("" ::: "memory");                                            \
    if ((T) + 2 < KTILES) {                                                   \
      asm volatile("s_waitcnt vmcnt(4)" ::: "memory");                        \
      __builtin_amdgcn_s_barrier();                                           \
    } else if ((T) + 1 < KTILES) {                                            \
      asm volatile("s_waitcnt vmcnt(0)" ::: "memory");                        \
      __builtin_amdgcn_s_barrier();                                           \
    }                                                                         \
    asm volatile("" ::: "memory");                                            \
  } while (0)

__global__ __launch_bounds__(512, 2) void mpo_gemm256(
    const unsigned short* __restrict__ Xb,
    const unsigned short* __restrict__ Mt,
    const float* __restrict__ bias,
    float* __restrict__ out) {
  extern __shared__ __align__(16) unsigned short sm[];
  unsigned short* smA = sm;                 // 4 slots x 8192 el (par, half)
  unsigned short* smB = sm + 4 * 8192;      // 4 slots x 8192 el
  const int tid = threadIdx.x;
  const int lane = tid & 63;
  const int wave = tid >> 6;                // 0..7
  const int bn = blockIdx.x;                // 0..11
  const int bm = blockIdx.y;                // 0..127

  // ---- staging addressing (pre-swizzled global source, linear LDS dest)
  const int lrow = lane >> 3;               // 0..7
  const int segg = (lane & 7) ^ lrow;       // swizzled global k-segment
  const unsigned short* gA = Xb + (size_t)(bm * 256 + wave * 16 + lrow) * 768 + segg * 8;
  const unsigned short* gB = Mt + (size_t)(bn * 256 + wave * 16 + lrow) * 768 + segg * 8;

  // ---- compute addressing
  const int wm = wave >> 2;                 // 0..1 (M half)
  const int wn = wave & 3;                  // 0..3 (N quarter)
  const int hb = wn >> 1;                   // B half
  const int row15 = lane & 15;
  const int kg = lane >> 4;                 // 0..3
  const int sp0 = ((0 * 4 + kg) ^ (row15 & 7)) * 8;
  const int sp1 = ((1 * 4 + kg) ^ (row15 & 7)) * 8;

  floatx4 acc[8][4];
#pragma unroll
  for (int mi = 0; mi < 8; mi++)
#pragma unroll
    for (int ni = 0; ni < 4; ni++) acc[mi][ni] = (floatx4){0.f, 0.f, 0.f, 0.f};

  // ---- prologue: stage tile0 fully + B(1); keep B(1) outstanding
  STAGE_A(0, 0, 0); STAGE_A(0, 1, 0);
  STAGE_B(0, 0, 0); STAGE_B(0, 1, 0);
  STAGE_B(1, 0, 1); STAGE_B(1, 1, 1);
  asm volatile("s_waitcnt vmcnt(4)" ::: "memory");
  __builtin_amdgcn_s_barrier();
  asm volatile("" ::: "memory");

  // ---- main loop: 12 K-tiles, parity-unrolled
  for (int t = 0; t < KTILES; t += 2) {
    TILE_STEP(t, 0);
    TILE_STEP(t + 1, 1);
  }

  // ---- epilogue: C/D layout col=lane&15, row=(lane>>4)*4+reg
  const int crow = (lane >> 4) * 4;
  const int ccol = lane & 15;
#pragma unroll
  for (int ni = 0; ni < 4; ni++) {
    int col = bn * 256 + wn * 64 + ni * 16 + ccol;
    float bv = bias[col];
#pragma unroll
    for (int mi = 0; mi < 8; mi++) {
      int row0 = bm * 256 + wm * 128 + mi * 16 + crow;
      floatx4 v = acc[mi][ni];
#pragma unroll
      for (int r = 0; r < 4; r++)
        out[(size_t)(row0 + r) * 3072 + col] = v[r] + bv;
    }
  }
}

// ---------------- workspace layout (bytes) ----------------
#define OFF_T2  0u                      // 147,456 B   (t2: 192*192 fp32)
#define OFF_T3  147456u                 // 9,437,184 B (t3: 6144*384 fp32)
#define OFF_B34 9584640u                // 589,824 B   (B34: 384*384 fp32)
#define OFF_MT  10174464u               // 4,718,592 B (Mt: 3072*768 bf16)
#define OFF_XB  14893056u               // 50,331,648 B (xb: 32768*768 bf16)
// total: 65,224,704 B

extern "C" void kernel_launch(void* const* d_in, const int* in_sizes, int n_in,
                              void* d_out, int out_size, void* d_ws, size_t ws_size,
                              hipStream_t stream) {
  const float* x  = (const float*)d_in[0];
  const float* c0 = (const float*)d_in[1];
  const float* c1 = (const float*)d_in[2];
  const float* c2 = (const float*)d_in[3];
  const float* c3 = (const float*)d_in[4];
  const float* c4 = (const float*)d_in[5];
  const float* bias = (const float*)d_in[6];
  float* out = (float*)d_out;
  char* ws = (char*)d_ws;

  float* t2 = (float*)(ws + OFF_T2);
  float* t3 = (float*)(ws + OFF_T3);
  float* B34 = (float*)(ws + OFF_B34);
  unsigned short* Mt = (unsigned short*)(ws + OFF_MT);
  unsigned short* xb = (unsigned short*)(ws + OFF_XB);

  // allow 128KB dynamic LDS for the 8-phase kernel (idempotent, non-stream op)
  (void)hipFuncSetAttribute((const void*)mpo_gemm256,
                            hipFuncAttributeMaxDynamicSharedMemorySize,
                            131072);

  // 1) x -> bf16
  cast_x_kernel<<<dim3(24576), dim3(256), 0, stream>>>(
      (const float4*)x, (ushort4*)xb, 6291456);

  // 2) step1 (tiny): c0 x c1 -> t2 [192,192]
  tt_gemm<<<dim3(48, 1), dim3(256), 0, stream>>>(
      c0, c1, t2, nullptr, 12, 12, 3072, 4, 4, 4, 192, 0);

  // 3) B34 = c3 x c4 -> [384, 384]
  b34_build<<<dim3(576), dim3(256), 0, stream>>>(c3, c4, B34);

  // 4) step2: t2 @ c2 -> t3 [6144, 384]
  tt_fast<2><<<dim3(96, 3), dim3(256), 0, stream>>>(t2, c2, t3, nullptr);

  // 5) step3': t3 @ B34 -> Mt bf16
  tt_fast<3><<<dim3(3, 96), dim3(256), 0, stream>>>(t3, B34, nullptr, Mt);

  // 6) main GEMM: grid (N/256=12, M/256=128), 512 thr, 128KB dynamic LDS
  mpo_gemm256<<<dim3(12, 128), dim3(512), 131072, stream>>>(xb, Mt, bias, out);
}